// Round 6
// baseline (1085.781 us; speedup 1.0000x reference)
//
#include <hip/hip_runtime.h>
#include <math.h>

#define HID 384
#define SLEN 128
#define NB 512
#define MTOK (NB*SLEN)   // 65536 tokens
#define NLAB 32
#define NSLOT 128
#define GPITCH 72        // LDS fp16 pitch (64 K + 8 pad): 144B stride = 2-way bank alias (free)

typedef _Float16 h8 __attribute__((ext_vector_type(8)));
typedef _Float16 h4v __attribute__((ext_vector_type(4)));
typedef __bf16   b8 __attribute__((ext_vector_type(8)));
typedef float    f4 __attribute__((ext_vector_type(4)));

// ---- NaN-proof primitives ----
__device__ __forceinline__ float sane(float x){
  return __builtin_isfinite(x) ? x : 0.f;
}
__device__ __forceinline__ float clampf(float x, float lo, float hi){
  return fminf(hi, fmaxf(lo, x));                      // NaN -> lo (finite)
}
__device__ __forceinline__ float fast_rcp(float x){
  return __builtin_amdgcn_rcpf(x);
}
__device__ __forceinline__ float fast_tanh(float x){
  x = clampf(x, -15.f, 15.f);
  float e = __expf(2.f * x);
  return (e - 1.f) * fast_rcp(e + 1.f);
}
__device__ __forceinline__ float sigmoid_c(float x){
  x = clampf(x, -60.f, 60.f);
  return fast_rcp(1.f + __expf(-x));
}
__device__ __forceinline__ void split16(float x, _Float16* h, _Float16* l){
  _Float16 hh = (_Float16)x; *h = hh; *l = (_Float16)(x - (float)hh);
}
__device__ __forceinline__ h8 ldh(const _Float16* p){ return *reinterpret_cast<const h8*>(p); }
__device__ __forceinline__ b8 ldb(const __bf16* p){ return *reinterpret_cast<const b8*>(p); }
__device__ __forceinline__ f4 mfma16h(h8 a, h8 b, f4 c){
  return __builtin_amdgcn_mfma_f32_16x16x32_f16(a, b, c, 0, 0, 0);
}
__device__ __forceinline__ f4 mfma16b(b8 a, b8 b, f4 c){
  return __builtin_amdgcn_mfma_f32_16x16x32_bf16(a, b, c, 0, 0, 0);
}
// LDS-only barrier: waits LDS ops, does NOT drain vmcnt -> global loads
// (A prefetch, B frags, epilogue) stay in flight across it. All global
// loads in the kernels using this are thread-private (register dest),
// so no cross-thread visibility is needed. llvm.amdgcn.s.barrier is a
// memory clobber at IR level, so LDS ops won't be moved across it.
__device__ __forceinline__ void bar_lds(){
  asm volatile("s_waitcnt lgkmcnt(0)" ::: "memory");
  __builtin_amdgcn_s_barrier();
}

// ---------------- setup kernels ----------------

__global__ void k_lens(const int* __restrict__ raw, int* __restrict__ lensN){
  const int b = threadIdx.x;          // block = NB = 512
  __shared__ int is64;
  if (b == 0) is64 = (raw[1] == 0) ? 1 : 0;
  __syncthreads();
  int v = is64 ? raw[2 * b] : raw[b];
  v = v < 0 ? 0 : (v > SLEN ? SLEN : v);
  lensN[b] = v;
}

// transposed fp16 hi/lo split
__global__ void k_wsplit16(const float* __restrict__ in, _Float16* __restrict__ outh,
                           _Float16* __restrict__ outl, int R, int C){
  int idx = blockIdx.x * blockDim.x + threadIdx.x;
  if (idx < R * C){
    int r = idx / C, c = idx - r * C;
    float v = sane(in[idx]);
    _Float16 h = (_Float16)v;
    outh[(size_t)c * R + r] = h;
    outl[(size_t)c * R + r] = (_Float16)(v - (float)h);
  }
}

// transposed bf16 hi/lo split (slot head weights)
__global__ void k_wsplitbf(const float* __restrict__ in, __bf16* __restrict__ outh,
                           __bf16* __restrict__ outl, int R, int C){
  int idx = blockIdx.x * blockDim.x + threadIdx.x;
  if (idx < R * C){
    int r = idx / C, c = idx - r * C;
    float v = sane(in[idx]);
    __bf16 h = (__bf16)v;
    outh[(size_t)c * R + r] = h;
    outl[(size_t)c * R + r] = (__bf16)(v - (float)h);
  }
}

__global__ void k_transpose32(const float* __restrict__ in, float* __restrict__ out,
                              int R, int C){
  int idx = blockIdx.x * blockDim.x + threadIdx.x;
  if (idx < R * C){ int r = idx / C, c = idx - r * C; out[(size_t)c * R + r] = sane(in[idx]); }
}

// sanitize-copy (keeps dot-phase weights in original [k][t] layout, coalesced)
__global__ void k_sanecopy(const float* __restrict__ in, float* __restrict__ out, int n){
  int i = blockIdx.x * blockDim.x + threadIdx.x;
  if (i < n) out[i] = sane(in[i]);
}

__global__ void k_w35(const float* __restrict__ W3, const float* __restrict__ W4,
                      const float* __restrict__ b4, const float* __restrict__ W5,
                      float* __restrict__ w35, float* __restrict__ w45, float* __restrict__ b45){
  __shared__ float w5s[HID];
  int t = threadIdx.x;                     // block = 384
  w5s[t] = sane(W5[t]);
  __syncthreads();
  float s3 = 0.f, s4 = 0.f;
  for (int j = 0; j < HID; ++j){
    float w5 = w5s[j];
    s3 += sane(W3[(size_t)t * HID + j]) * w5;
    s4 += sane(W4[(size_t)t * HID + j]) * w5;
  }
  w35[t] = s3; w45[t] = s4;
  if (t == 0){
    float s = 0.f;
    for (int j = 0; j < HID; ++j) s += sane(b4[j]) * w5s[j];
    *b45 = s;
  }
}

__global__ void k_ci(const float* __restrict__ ci, float* __restrict__ r_inte){
  size_t i = blockIdx.x * (size_t)blockDim.x + threadIdx.x;
  if (i < (size_t)NB * HID) r_inte[i] = sane(ci[i]);
}

__global__ void k_hy(const float* __restrict__ Hm, const float* __restrict__ w45,
                     const float* __restrict__ b45, float* __restrict__ hy){
  int wave = threadIdx.x >> 6, lane = threadIdx.x & 63;
  int tok = blockIdx.x * 4 + wave;
  const float* row = Hm + (size_t)tok * HID;
  float s = 0.f;
#pragma unroll
  for (int i = 0; i < 6; ++i){ int k = lane + 64 * i; s += sane(row[k]) * w45[k]; }
  for (int off = 32; off; off >>= 1) s += __shfl_down(s, off);
  if (lane == 0) hy[tok] = clampf(s + *b45, -1e30f, 1e30f);
}

// ---------------- per-iteration small GEMM (fp32, used once for initial yw1) ----
template <int TANH>
__global__ void k_vecmat(const float* __restrict__ in, const float* __restrict__ W,
                         float* __restrict__ out, float* __restrict__ pre_store){
  const int b = blockIdx.x, t = threadIdx.x;   // block = 384
  __shared__ float v[HID];
  float x = in[(size_t)b * HID + t];
  if (TANH) x = fast_tanh(x);
  v[t] = x;
  if (pre_store) pre_store[(size_t)b * HID + t] = x;
  __syncthreads();
  float s = 0.f;
  for (int k = 0; k < HID; ++k) s += v[k] * W[(size_t)k * HID + t];
  out[(size_t)b * HID + t] = clampf(s, -1e30f, 1e30f);
}

// ---------------- P0 = tanh(Cs) @ W0 (setup) ----------------
// v2: g2n-proven structure. 512 thr / 8 waves x 48 cols / 64-row blocks
// (grid 1024, dead-block skip). A-stage reads Cs fp32 + tanh + hi/lo split
// ONCE (the old (NB,3) grid recomputed it 3x). B = W0 hi/lo direct from L2.
// Relaxed barriers (bar_lds) + register prefetch of next K-step's Cs: global
// loads stay in flight across barriers, latency hides under the MFMA phase.
// MFMA accumulation order per output is unchanged -> bit-identical P0.
__global__ void __launch_bounds__(512, 4) k_p0c(
    const float* __restrict__ Cs,
    const _Float16* __restrict__ Wth, const _Float16* __restrict__ Wtl,
    const int* __restrict__ lens,
    _Float16* __restrict__ P0h, _Float16* __restrict__ P0l){
  __shared__ _Float16 Ah[64*GPITCH], Al[64*GPITCH];   // 9 KB each
  const int t = threadIdx.x;
  const int wave = t >> 6, lane = t & 63, quad = lane >> 4, lr = lane & 15;
  const int bx = blockIdx.x;           // 64-row group (half sentence)
  const int b = bx >> 1;
  const int len = lens[b];
  const int row0 = (bx & 1) * 64;
  if (row0 >= len) return;             // dead half: P0 rows never read live
  const int gr0 = bx * 64;
  const int srow = t >> 3;             // staging: 8 threads/row, 8 K-els each
  const int sk8 = (t & 7) << 3;
  const int col0 = wave * 48;
  const float* abase = Cs + (size_t)(gr0 + srow) * HID + sk8;
  f4 c0 = *(const f4*)(abase);
  f4 c1 = *(const f4*)(abase + 4);
  f4 acc[4][3] = {};
  for (int ks = 0; ks < 6; ++ks){
    const int kk = ks * 64;
    {   // A-stage: tanh + hi/lo split (once per row, was 3x)
      h8 th, tl;
#pragma unroll
      for (int j = 0; j < 8; ++j){
        float x = fast_tanh(sane((j < 4) ? c0[j] : c1[j - 4]));
        _Float16 h = (_Float16)x;
        th[j] = h; tl[j] = (_Float16)(x - (float)h);
      }
      *(h8*)&Ah[srow * GPITCH + sk8] = th;
      *(h8*)&Al[srow * GPITCH + sk8] = tl;
    }
    if (ks < 5){                       // prefetch next K-step (hides under MFMA)
      c0 = *(const f4*)(abase + kk + 64);
      c1 = *(const f4*)(abase + kk + 68);
    }
    bar_lds();
#pragma unroll
    for (int c = 0; c < 2; ++c){
      const int ro = c * 32 + quad * 8;
      h8 amh[4], aml[4];
#pragma unroll
      for (int mi = 0; mi < 4; ++mi){
        const int r = (mi * 16 + lr) * GPITCH + ro;
        amh[mi] = *(const h8*)&Ah[r]; aml[mi] = *(const h8*)&Al[r];
      }
#pragma unroll
      for (int ni = 0; ni < 3; ++ni){
        const size_t rb = ((size_t)(col0 + ni * 16 + lr)) * HID + kk + ro;
        h8 bh = ldh(Wth + rb), bl = ldh(Wtl + rb);   // L2-resident weights
#pragma unroll
        for (int mi = 0; mi < 4; ++mi){
          acc[mi][ni] = mfma16h(amh[mi], bh, acc[mi][ni]);
          acc[mi][ni] = mfma16h(amh[mi], bl, acc[mi][ni]);
          acc[mi][ni] = mfma16h(aml[mi], bh, acc[mi][ni]);
        }
      }
    }
    bar_lds();
  }
  // epilogue: split-store live rows of the wave's 48 cols
#pragma unroll
  for (int ni = 0; ni < 3; ++ni){
    const int col = col0 + ni * 16 + lr;
#pragma unroll
    for (int mi = 0; mi < 4; ++mi)
#pragma unroll
      for (int r = 0; r < 4; ++r){
        const int rl = row0 + mi * 16 + quad * 4 + r;
        if (rl < len){
          const size_t o = ((size_t)(b * SLEN + rl)) * HID + col;
          _Float16 h, l; split16(acc[mi][ni][r], &h, &l);
          P0h[o] = h; P0l[o] = l;
        }
      }
  }
}

// ---------------- G2 (per iteration): 64 rows x full N=384 per block -------------
// Round-3 proven tile (512 thr, 8 waves x 48 cols, acc[4][3], 2 blk/CU), plus:
// relaxed bar_lds barriers (no vmcnt drain) + register prefetch of next
// K-step's P0 pair -> HBM latency hides under the 36-MFMA phase.
__global__ void __launch_bounds__(512, 4) k_g2n(
    const _Float16* __restrict__ P0h, const _Float16* __restrict__ P0l,
    const _Float16* __restrict__ Wth, const _Float16* __restrict__ Wtl,
    const float* __restrict__ yw1, const float* __restrict__ Cs,
    const float* __restrict__ r_inte,
    const int* __restrict__ lens, float* __restrict__ S){
  __shared__ _Float16 Ah[64*GPITCH], Al[64*GPITCH];   // 9 KB each
  __shared__ float ywS[HID];                          // 1.5 KB
  const int t = threadIdx.x;
  const int wave = t >> 6, lane = t & 63, quad = lane >> 4, lr = lane & 15;
  const int bx = blockIdx.x;           // 64-row group (half sentence)
  const int b = bx >> 1;
  const int len = lens[b];
  const int row0 = (bx & 1) * 64;
  if (row0 >= len) return;             // whole block padding: contributes 0 to S
  const int gr0 = bx * 64;
  const int srow = t >> 3;
  const int sk8 = (t & 7) << 3;
  const int col0 = wave * 48;
  if (t < HID) ywS[t] = yw1[(size_t)b * HID + t];
  __syncthreads();
  const _Float16* pbase = P0h + (size_t)(gr0 + srow) * HID + sk8;
  const _Float16* lbase = P0l + (size_t)(gr0 + srow) * HID + sk8;
  h8 ph = ldh(pbase), pl = ldh(lbase);
  f4 acc[4][3] = {};
  for (int ks = 0; ks < 6; ++ks){
    const int kk = ks * 64;
    {   // A-stage: T = tanh(P0.hi + P0.lo + yw1), split to hi/lo planes
      const f4 ywa = *(const f4*)&ywS[kk + sk8];
      const f4 ywb = *(const f4*)&ywS[kk + sk8 + 4];
      h8 th, tl;
#pragma unroll
      for (int j = 0; j < 8; ++j){
        const float yw = (j < 4) ? ywa[j] : ywb[j - 4];
        float x = fast_tanh((float)ph[j] + (float)pl[j] + yw);
        _Float16 h = (_Float16)x;
        th[j] = h; tl[j] = (_Float16)(x - (float)h);
      }
      *(h8*)&Ah[srow * GPITCH + sk8] = th;
      *(h8*)&Al[srow * GPITCH + sk8] = tl;
    }
    if (ks < 5){                       // prefetch next K-step's P0 pair
      ph = ldh(pbase + kk + 64);
      pl = ldh(lbase + kk + 64);
    }
    bar_lds();
#pragma unroll
    for (int c = 0; c < 2; ++c){
      const int ro = c * 32 + quad * 8;
      h8 amh[4], aml[4];
#pragma unroll
      for (int mi = 0; mi < 4; ++mi){
        const int r = (mi * 16 + lr) * GPITCH + ro;
        amh[mi] = *(const h8*)&Ah[r]; aml[mi] = *(const h8*)&Al[r];
      }
#pragma unroll
      for (int ni = 0; ni < 3; ++ni){
        const size_t rb = ((size_t)(col0 + ni * 16 + lr)) * HID + kk + ro;
        h8 bh = ldh(Wth + rb), bl = ldh(Wtl + rb);   // L2-resident weights
#pragma unroll
        for (int mi = 0; mi < 4; ++mi){
          acc[mi][ni] = mfma16h(amh[mi], bh, acc[mi][ni]);
          acc[mi][ni] = mfma16h(amh[mi], bl, acc[mi][ni]);
          acc[mi][ni] = mfma16h(aml[mi], bh, acc[mi][ni]);
        }
      }
    }
    bar_lds();
  }
  const float* rb = r_inte + (size_t)b * HID;
#pragma unroll
  for (int ni = 0; ni < 3; ++ni){
    const int col = col0 + ni * 16 + lr;
    const float yv = rb[col];
    const float y0 = fast_tanh(yv);
    float csum = 0.f;
#pragma unroll
    for (int mi = 0; mi < 4; ++mi)
#pragma unroll
      for (int r = 0; r < 4; ++r){
        const int rl = row0 + mi * 16 + quad * 4 + r;       // within sentence
        const int grow = gr0 + mi * 16 + quad * 4 + r;      // global token row
        const float f = sigmoid_c(acc[mi][ni][r]);
        const float omf = 1.f - f;
        const float xv = sane(Cs[(size_t)grow * HID + col]);
        const float x0 = fast_tanh(xv);
        const float outv = f * f * x0 + f * xv + omf * omf * y0 + omf * yv;
        csum += (rl < len) ? outv : 0.f;
      }
    csum += __shfl_xor(csum, 16);
    csum += __shfl_xor(csum, 32);
    if (quad == 0) atomicAdd(&S[(size_t)b * HID + col], csum);
  }
}

// ---------------- stage D v2: fss -> rates -> softmax -> f_inte -> r_inte -> yw1 ----
__global__ void k_stageD2(
    const float* __restrict__ Cs, const float* __restrict__ Hm,
    const float* __restrict__ ci, const float* __restrict__ Vsc,
    const float* __restrict__ W1c, const float* __restrict__ w35,
    const float* __restrict__ hy, const int* __restrict__ lens,
    float* __restrict__ S, float* __restrict__ fss_g,
    float* __restrict__ r_inte, float* __restrict__ yw1){
  const int b = blockIdx.x;
  const int t = threadIdx.x;            // 384 threads = 6 waves
  const int len = lens[b];
  __shared__ float Sl[HID], fssS[HID], fssw[HID], tri[HID];
  __shared__ float rates[SLEN];
  __shared__ float wA[SLEN], wB[SLEN], wC[SLEN], wD[SLEN];
  // phase 0: fss = S @ V_SF; zero S for next iteration
  Sl[t] = S[(size_t)b * HID + t];
  S[(size_t)b * HID + t] = 0.f;
  __syncthreads();
  {
    float s = 0.f;
    for (int k = 0; k < HID; ++k) s += Sl[k] * Vsc[(size_t)k * HID + t];
    const float fs = clampf(s, -1e30f, 1e30f);
    fssS[t] = fs; fssw[t] = fs * w35[t];
    fss_g[(size_t)b * HID + t] = fs;
  }
  __syncthreads();
  // phase 1: rates
  const int wave = t >> 6, lane = t & 63;
  for (int l = wave; l < SLEN; l += 6){
    const float* row = Cs + ((size_t)b * SLEN + l) * HID;
    float s = 0.f;
#pragma unroll
    for (int i = 0; i < 6; ++i){ int k = lane + 64 * i; s += sane(row[k]) * fssw[k]; }
    for (int off = 32; off; off >>= 1) s += __shfl_down(s, off);
    if (lane == 0) rates[l] = clampf(s + hy[(size_t)b * SLEN + l], -1e30f, 1e30f);
  }
  __syncthreads();
  // phase 2: masked softmax -> fusion weights
  if (wave == 0){
    float r0 = (lane < len) ? rates[lane] : -3.0e38f;
    float r1 = (lane + 64 < len) ? rates[lane + 64] : -3.0e38f;
    float mx = fmaxf(r0, r1);
    for (int off = 32; off; off >>= 1) mx = fmaxf(mx, __shfl_xor(mx, off));
    float e0 = (lane < len) ? __expf(r0 - mx) : 0.f;
    float e1 = (lane + 64 < len) ? __expf(r1 - mx) : 0.f;
    float sm = e0 + e1;
    for (int off = 32; off; off >>= 1) sm += __shfl_xor(sm, off);
    const float inv = (sm > 0.f) ? (1.f / sm) : 0.f;
    float a0 = clampf(e0 * inv, 0.f, 1.f), a1 = clampf(e1 * inv, 0.f, 1.f);
    wA[lane] = a0 * a0; wB[lane] = a0;
    wC[lane] = (1.f - a0) * (1.f - a0); wD[lane] = 1.f - a0;
    wA[lane + 64] = a1 * a1; wB[lane + 64] = a1;
    wC[lane + 64] = (1.f - a1) * (1.f - a1); wD[lane + 64] = 1.f - a1;
  }
  __syncthreads();
  // phase 3: f_inte -> r_inte
  {
    const float fs = fssS[t];
    float acc = 0.f;
#pragma unroll 4
    for (int l = 0; l < len; ++l){
      const float cv = sane(Cs[((size_t)b * SLEN + l) * HID + t]);
      const float hv = sane(Hm[((size_t)b * SLEN + l) * HID + t]);
      const float rs = fs * cv;
      acc += wA[l] * fast_tanh(rs) + wB[l] * rs + wC[l] * fast_tanh(hv) + wD[l] * hv;
    }
    const float ri = clampf(acc + sane(ci[(size_t)b * HID + t]), -1e30f, 1e30f);
    r_inte[(size_t)b * HID + t] = ri;
    tri[t] = fast_tanh(ri);
  }
  __syncthreads();
  // phase 4: next-iteration yw1 = tanh(r_inte) @ W1
  {
    float s = 0.f;
    for (int k = 0; k < HID; ++k) s += tri[k] * W1c[(size_t)k * HID + t];
    yw1[(size_t)b * HID + t] = clampf(s, -1e30f, 1e30f);
  }
}

// ---------------- output heads (fp32 outputs) ----------------
__global__ void k_intent(const float* __restrict__ r_inte, const float* __restrict__ Wit,
                         float* __restrict__ out){
  const int t = threadIdx.x;                 // block 128: 4 sentences x 32 labels
  const int b = blockIdx.x * 4 + (t >> 5);
  const int n = t & 31;
  const float* wr = Wit + (size_t)n * HID;
  const float* rr = r_inte + (size_t)b * HID;
  float s = 0.f;
  for (int k = 0; k < HID; ++k) s += rr[k] * wr[k];
  out[(size_t)b * NLAB + n] = clampf(s, -3e38f, 3e38f);
}

// slot_output = [H | fss(b).*c] @ W_slot, split-bf16 3-product, dead waves write 0.
__global__ void __launch_bounds__(256, 2) k_slot_bf(
    const float* __restrict__ Hm, const float* __restrict__ Cs,
    const float* __restrict__ fss, const int* __restrict__ lens,
    const __bf16* __restrict__ Wth, const __bf16* __restrict__ Wtl,
    float* __restrict__ out){
  const int wave = threadIdx.x >> 6, lane = threadIdx.x & 63;
  const int quad = lane >> 4, lr = lane & 15;
  const int m0 = blockIdx.x * 128 + (wave & 1) * 64;
  const int n0 = (wave >> 1) * 64;
  const int b = blockIdx.x;
  const int ko = quad * 8;
  const int len = lens[b];
  if ((wave & 1) * 64 >= len){
#pragma unroll
    for (int mi = 0; mi < 4; ++mi)
#pragma unroll
      for (int ni = 0; ni < 4; ++ni)
#pragma unroll
        for (int r = 0; r < 4; ++r){
          const int row = m0 + mi * 16 + quad * 4 + r;
          const int col = n0 + ni * 16 + lr;
          out[(size_t)row * NSLOT + col] = 0.f;
        }
    return;
  }
  f4 acc[4][4] = {};
  for (int kk = 0; kk < 2 * HID; kk += 32){
    b8 ah[4], al[4], bh[4], bl[4];
#pragma unroll
    for (int i = 0; i < 4; ++i){
      size_t rb = (size_t)(n0 + i * 16 + lr) * (2 * HID) + kk + ko;
      bh[i] = ldb(Wth + rb); bl[i] = ldb(Wtl + rb);
    }
    if (kk < HID){
#pragma unroll
      for (int i = 0; i < 4; ++i){
        const float* hrow = Hm + (size_t)(m0 + i * 16 + lr) * HID + kk + ko;
        b8 vh, vl;
#pragma unroll
        for (int j = 0; j < 8; ++j){
          float v = sane(hrow[j]);
          __bf16 h = (__bf16)v;
          vh[j] = h; vl[j] = (__bf16)(v - (float)h);
        }
        ah[i] = vh; al[i] = vl;
      }
    } else {
      const int k2 = kk - HID + ko;
      float fv[8];
#pragma unroll
      for (int j = 0; j < 8; ++j) fv[j] = fss[(size_t)b * HID + k2 + j];
#pragma unroll
      for (int i = 0; i < 4; ++i){
        const float* crow = Cs + (size_t)(m0 + i * 16 + lr) * HID + k2;
        b8 vh, vl;
#pragma unroll
        for (int j = 0; j < 8; ++j){
          float v = fv[j] * sane(crow[j]);
          __bf16 h = (__bf16)v;
          vh[j] = h; vl[j] = (__bf16)(v - (float)h);
        }
        ah[i] = vh; al[i] = vl;
      }
    }
#pragma unroll
    for (int mi = 0; mi < 4; ++mi)
#pragma unroll
      for (int ni = 0; ni < 4; ++ni){
        acc[mi][ni] = mfma16b(ah[mi], bh[ni], acc[mi][ni]);
        acc[mi][ni] = mfma16b(ah[mi], bl[ni], acc[mi][ni]);
        acc[mi][ni] = mfma16b(al[mi], bh[ni], acc[mi][ni]);
      }
  }
#pragma unroll
  for (int mi = 0; mi < 4; ++mi)
#pragma unroll
    for (int ni = 0; ni < 4; ++ni)
#pragma unroll
      for (int r = 0; r < 4; ++r){
        const int row = m0 + mi * 16 + quad * 4 + r;
        const int col = n0 + ni * 16 + lr;
        out[(size_t)row * NSLOT + col] = clampf(acc[mi][ni][r], -3e38f, 3e38f);
      }
}

// ---------------- launch ----------------
extern "C" void kernel_launch(void* const* d_in, const int* in_sizes, int n_in,
                              void* d_out, int out_size, void* d_ws, size_t ws_size,
                              hipStream_t stream){
  (void)in_sizes; (void)n_in; (void)out_size;
  const float* Hm  = (const float*)d_in[0];
  const float* Cs  = (const float*)d_in[1];
  const float* ci  = (const float*)d_in[2];
  const float* W0  = (const float*)d_in[3];
  const float* W1  = (const float*)d_in[4];
  const float* W2  = (const float*)d_in[5];
  const float* W3  = (const float*)d_in[6];
  const float* W4  = (const float*)d_in[7];
  const float* b4  = (const float*)d_in[8];
  const float* W5  = (const float*)d_in[9];
  const float* Vs  = (const float*)d_in[10];
  const float* Wi  = (const float*)d_in[11];
  const float* Wsl = (const float*)d_in[12];
  const int* lens_raw = (const int*)d_in[13];
  // d_in[14] = iteration_num = 3 (hard-coded)

  char* base = (char*)d_ws;
  size_t off = 0;
  auto alloc = [&](size_t bytes) -> void* {
    void* p = base + off; off += (bytes + 255) & ~(size_t)255; return p;
  };
  const size_t NT = (size_t)MTOK * HID;
  _Float16* P0h  = (_Float16*)alloc(NT * 2);
  _Float16* P0l  = (_Float16*)alloc(NT * 2);
  _Float16* W0th = (_Float16*)alloc((size_t)HID * HID * 2);
  _Float16* W0tl = (_Float16*)alloc((size_t)HID * HID * 2);
  _Float16* W2th = (_Float16*)alloc((size_t)HID * HID * 2);
  _Float16* W2tl = (_Float16*)alloc((size_t)HID * HID * 2);
  __bf16*   Wsth = (__bf16*)alloc((size_t)2 * HID * NSLOT * 2);
  __bf16*   Wstl = (__bf16*)alloc((size_t)2 * HID * NSLOT * 2);
  float* W1c    = (float*)alloc((size_t)HID * HID * 4);
  float* Vsc    = (float*)alloc((size_t)HID * HID * 4);
  float* Wit    = (float*)alloc((size_t)HID * NLAB * 4);
  float* w35    = (float*)alloc(HID * 4);
  float* w45    = (float*)alloc(HID * 4);
  float* b45    = (float*)alloc(4);
  float* hy     = (float*)alloc((size_t)MTOK * 4);
  float* yw1    = (float*)alloc((size_t)NB * HID * 4);
  float* r_inte = (float*)alloc((size_t)NB * HID * 4);
  float* S      = (float*)alloc((size_t)NB * HID * 4);
  float* fss    = (float*)alloc((size_t)NB * HID * 4);
  int* lensN    = (int*)alloc((size_t)NB * 4);
  if (off > ws_size) return;

  k_lens<<<1, NB, 0, stream>>>(lens_raw, lensN);
  k_wsplit16<<<(HID * HID + 255) / 256, 256, 0, stream>>>(W0, W0th, W0tl, HID, HID);
  k_wsplit16<<<(HID * HID + 255) / 256, 256, 0, stream>>>(W2, W2th, W2tl, HID, HID);
  k_wsplitbf<<<(2 * HID * NSLOT + 255) / 256, 256, 0, stream>>>(Wsl, Wsth, Wstl, 2 * HID, NSLOT);
  k_sanecopy<<<(HID * HID + 255) / 256, 256, 0, stream>>>(W1, W1c, HID * HID);
  k_sanecopy<<<(HID * HID + 255) / 256, 256, 0, stream>>>(Vs, Vsc, HID * HID);
  k_transpose32<<<(HID * NLAB + 255) / 256, 256, 0, stream>>>(Wi, Wit, HID, NLAB);
  k_w35<<<1, HID, 0, stream>>>(W3, W4, b4, W5, w35, w45, b45);
  k_ci<<<(NB * HID + 255) / 256, 256, 0, stream>>>(ci, r_inte);
  k_hy<<<MTOK / 4, 256, 0, stream>>>(Hm, w45, b45, hy);
  k_p0c<<<MTOK / 64, 512, 0, stream>>>(Cs, W0th, W0tl, lensN, P0h, P0l);

  // initial yw1 = tanh(r_inte) @ W1 (subsequent ones computed in k_stageD2 tail)
  k_vecmat<1><<<NB, HID, 0, stream>>>(r_inte, W1c, yw1, (float*)nullptr);
  hipMemsetAsync(S, 0, (size_t)NB * HID * 4, stream);

  for (int it = 0; it < 3; ++it){
    k_g2n<<<MTOK / 64, 512, 0, stream>>>(P0h, P0l, W2th, W2tl, yw1, Cs, r_inte, lensN, S);
    k_stageD2<<<NB, HID, 0, stream>>>(Cs, Hm, ci, Vsc, W1c, w35, hy, lensN,
                                      S, fss, r_inte, yw1);
  }

  float* outp = (float*)d_out;
  k_intent<<<NB / 4, 128, 0, stream>>>(r_inte, Wit, outp);
  k_slot_bf<<<NB, 256, 0, stream>>>(Hm, Cs, fss, lensN, Wsth, Wstl, outp + (size_t)NB * NLAB);
}

// Round 7
// 997.183 us; speedup vs baseline: 1.0888x; 1.0888x over previous
//
#include <hip/hip_runtime.h>
#include <math.h>

#define HID 384
#define SLEN 128
#define NB 512
#define MTOK (NB*SLEN)   // 65536 tokens
#define NLAB 32
#define NSLOT 128
#define GPITCH 72        // LDS fp16 pitch (64 K + 8 pad): 144B stride = 2-way bank alias (free)

typedef _Float16 h8 __attribute__((ext_vector_type(8)));
typedef _Float16 h4v __attribute__((ext_vector_type(4)));
typedef __bf16   b8 __attribute__((ext_vector_type(8)));
typedef float    f4 __attribute__((ext_vector_type(4)));

// ---- NaN-proof primitives ----
__device__ __forceinline__ float sane(float x){
  return __builtin_isfinite(x) ? x : 0.f;
}
__device__ __forceinline__ float clampf(float x, float lo, float hi){
  return fminf(hi, fmaxf(lo, x));                      // NaN -> lo (finite)
}
__device__ __forceinline__ float fast_rcp(float x){
  return __builtin_amdgcn_rcpf(x);
}
__device__ __forceinline__ float fast_tanh(float x){
  x = clampf(x, -15.f, 15.f);
  float e = __expf(2.f * x);
  return (e - 1.f) * fast_rcp(e + 1.f);
}
__device__ __forceinline__ float sigmoid_c(float x){
  x = clampf(x, -60.f, 60.f);
  return fast_rcp(1.f + __expf(-x));
}
__device__ __forceinline__ void split16(float x, _Float16* h, _Float16* l){
  _Float16 hh = (_Float16)x; *h = hh; *l = (_Float16)(x - (float)hh);
}
__device__ __forceinline__ h8 ldh(const _Float16* p){ return *reinterpret_cast<const h8*>(p); }
__device__ __forceinline__ b8 ldb(const __bf16* p){ return *reinterpret_cast<const b8*>(p); }
__device__ __forceinline__ f4 mfma16h(h8 a, h8 b, f4 c){
  return __builtin_amdgcn_mfma_f32_16x16x32_f16(a, b, c, 0, 0, 0);
}
__device__ __forceinline__ f4 mfma16b(b8 a, b8 b, f4 c){
  return __builtin_amdgcn_mfma_f32_16x16x32_bf16(a, b, c, 0, 0, 0);
}
// LDS-only barrier: waits LDS ops, does NOT drain vmcnt -> global loads stay
// in flight across it. All global loads in kernels using this are
// thread-private (register dest), so no cross-thread visibility is needed.
__device__ __forceinline__ void bar_lds(){
  asm volatile("s_waitcnt lgkmcnt(0)" ::: "memory");
  __builtin_amdgcn_s_barrier();
}

// ---------------- setup kernels ----------------

__global__ void k_lens(const int* __restrict__ raw, int* __restrict__ lensN){
  const int b = threadIdx.x;          // block = NB = 512
  __shared__ int is64;
  if (b == 0) is64 = (raw[1] == 0) ? 1 : 0;
  __syncthreads();
  int v = is64 ? raw[2 * b] : raw[b];
  v = v < 0 ? 0 : (v > SLEN ? SLEN : v);
  lensN[b] = v;
}

// transposed fp16 hi/lo split
__global__ void k_wsplit16(const float* __restrict__ in, _Float16* __restrict__ outh,
                           _Float16* __restrict__ outl, int R, int C){
  int idx = blockIdx.x * blockDim.x + threadIdx.x;
  if (idx < R * C){
    int r = idx / C, c = idx - r * C;
    float v = sane(in[idx]);
    _Float16 h = (_Float16)v;
    outh[(size_t)c * R + r] = h;
    outl[(size_t)c * R + r] = (_Float16)(v - (float)h);
  }
}

// transposed bf16 hi/lo split (slot head weights)
__global__ void k_wsplitbf(const float* __restrict__ in, __bf16* __restrict__ outh,
                           __bf16* __restrict__ outl, int R, int C){
  int idx = blockIdx.x * blockDim.x + threadIdx.x;
  if (idx < R * C){
    int r = idx / C, c = idx - r * C;
    float v = sane(in[idx]);
    __bf16 h = (__bf16)v;
    outh[(size_t)c * R + r] = h;
    outl[(size_t)c * R + r] = (__bf16)(v - (float)h);
  }
}

__global__ void k_transpose32(const float* __restrict__ in, float* __restrict__ out,
                              int R, int C){
  int idx = blockIdx.x * blockDim.x + threadIdx.x;
  if (idx < R * C){ int r = idx / C, c = idx - r * C; out[(size_t)c * R + r] = sane(in[idx]); }
}

// sanitize-copy (keeps dot-phase weights in original [k][t] layout, coalesced)
__global__ void k_sanecopy(const float* __restrict__ in, float* __restrict__ out, int n){
  int i = blockIdx.x * blockDim.x + threadIdx.x;
  if (i < n) out[i] = sane(in[i]);
}

__global__ void k_w35(const float* __restrict__ W3, const float* __restrict__ W4,
                      const float* __restrict__ b4, const float* __restrict__ W5,
                      float* __restrict__ w35, float* __restrict__ w45, float* __restrict__ b45){
  __shared__ float w5s[HID];
  int t = threadIdx.x;                     // block = 384
  w5s[t] = sane(W5[t]);
  __syncthreads();
  float s3 = 0.f, s4 = 0.f;
  for (int j = 0; j < HID; ++j){
    float w5 = w5s[j];
    s3 += sane(W3[(size_t)t * HID + j]) * w5;
    s4 += sane(W4[(size_t)t * HID + j]) * w5;
  }
  w35[t] = s3; w45[t] = s4;
  if (t == 0){
    float s = 0.f;
    for (int j = 0; j < HID; ++j) s += sane(b4[j]) * w5s[j];
    *b45 = s;
  }
}

__global__ void k_hy(const float* __restrict__ Hm, const float* __restrict__ w45,
                     const float* __restrict__ b45, float* __restrict__ hy){
  int wave = threadIdx.x >> 6, lane = threadIdx.x & 63;
  int tok = blockIdx.x * 4 + wave;
  const float* row = Hm + (size_t)tok * HID;
  float s = 0.f;
#pragma unroll
  for (int i = 0; i < 6; ++i){ int k = lane + 64 * i; s += sane(row[k]) * w45[k]; }
  for (int off = 32; off; off >>= 1) s += __shfl_down(s, off);
  if (lane == 0) hy[tok] = clampf(s + *b45, -1e30f, 1e30f);
}

// ---------------- small GEMM (fp32). SANE_IN: sanitize input and store the
// sanitized pre-tanh value to pre_store (folds the old k_ci copy kernel). ----
template <int TANH, int SANE_IN>
__global__ void k_vecmat(const float* __restrict__ in, const float* __restrict__ W,
                         float* __restrict__ out, float* __restrict__ pre_store){
  const int b = blockIdx.x, t = threadIdx.x;   // block = 384
  __shared__ float v[HID];
  float x = in[(size_t)b * HID + t];
  if (SANE_IN) x = sane(x);
  if (pre_store) pre_store[(size_t)b * HID + t] = x;
  if (TANH) x = fast_tanh(x);
  v[t] = x;
  __syncthreads();
  float s = 0.f;
  for (int k = 0; k < HID; ++k) s += v[k] * W[(size_t)k * HID + t];
  out[(size_t)b * HID + t] = clampf(s, -1e30f, 1e30f);
}

// ---------------- P0 = tanh(Cs) @ W0 (setup) ----------------
// Round-6 structure (kept): 512 thr / 8 waves x 48 cols / 64-row blocks,
// single tanh+split, relaxed barriers, register prefetch.
__global__ void __launch_bounds__(512, 4) k_p0c(
    const float* __restrict__ Cs,
    const _Float16* __restrict__ Wth, const _Float16* __restrict__ Wtl,
    const int* __restrict__ lens,
    _Float16* __restrict__ P0h, _Float16* __restrict__ P0l){
  __shared__ _Float16 Ah[64*GPITCH], Al[64*GPITCH];   // 9 KB each
  const int t = threadIdx.x;
  const int wave = t >> 6, lane = t & 63, quad = lane >> 4, lr = lane & 15;
  const int bx = blockIdx.x;           // 64-row group (half sentence)
  const int b = bx >> 1;
  const int len = lens[b];
  const int row0 = (bx & 1) * 64;
  if (row0 >= len) return;             // dead half: P0 rows never read live
  const int gr0 = bx * 64;
  const int srow = t >> 3;             // staging: 8 threads/row, 8 K-els each
  const int sk8 = (t & 7) << 3;
  const int col0 = wave * 48;
  const float* abase = Cs + (size_t)(gr0 + srow) * HID + sk8;
  f4 c0 = *(const f4*)(abase);
  f4 c1 = *(const f4*)(abase + 4);
  f4 acc[4][3] = {};
  for (int ks = 0; ks < 6; ++ks){
    const int kk = ks * 64;
    {   // A-stage: tanh + hi/lo split (once per row)
      h8 th, tl;
#pragma unroll
      for (int j = 0; j < 8; ++j){
        float x = fast_tanh(sane((j < 4) ? c0[j] : c1[j - 4]));
        _Float16 h = (_Float16)x;
        th[j] = h; tl[j] = (_Float16)(x - (float)h);
      }
      *(h8*)&Ah[srow * GPITCH + sk8] = th;
      *(h8*)&Al[srow * GPITCH + sk8] = tl;
    }
    if (ks < 5){                       // prefetch next K-step (hides under MFMA)
      c0 = *(const f4*)(abase + kk + 64);
      c1 = *(const f4*)(abase + kk + 68);
    }
    bar_lds();
#pragma unroll
    for (int c = 0; c < 2; ++c){
      const int ro = c * 32 + quad * 8;
      h8 amh[4], aml[4];
#pragma unroll
      for (int mi = 0; mi < 4; ++mi){
        const int r = (mi * 16 + lr) * GPITCH + ro;
        amh[mi] = *(const h8*)&Ah[r]; aml[mi] = *(const h8*)&Al[r];
      }
#pragma unroll
      for (int ni = 0; ni < 3; ++ni){
        const size_t rb = ((size_t)(col0 + ni * 16 + lr)) * HID + kk + ro;
        h8 bh = ldh(Wth + rb), bl = ldh(Wtl + rb);   // L2-resident weights
#pragma unroll
        for (int mi = 0; mi < 4; ++mi){
          acc[mi][ni] = mfma16h(amh[mi], bh, acc[mi][ni]);
          acc[mi][ni] = mfma16h(amh[mi], bl, acc[mi][ni]);
          acc[mi][ni] = mfma16h(aml[mi], bh, acc[mi][ni]);
        }
      }
    }
    bar_lds();
  }
  // epilogue: split-store live rows of the wave's 48 cols
#pragma unroll
  for (int ni = 0; ni < 3; ++ni){
    const int col = col0 + ni * 16 + lr;
#pragma unroll
    for (int mi = 0; mi < 4; ++mi)
#pragma unroll
      for (int r = 0; r < 4; ++r){
        const int rl = row0 + mi * 16 + quad * 4 + r;
        if (rl < len){
          const size_t o = ((size_t)(b * SLEN + rl)) * HID + col;
          _Float16 h, l; split16(acc[mi][ni][r], &h, &l);
          P0h[o] = h; P0l[o] = l;
        }
      }
  }
}

// ---- G2 helpers: compile-time MI (4 for len<=64, 8 for len>64) -------------
template <int MI>
__device__ __forceinline__ void g2n_mfma(f4 (&acc)[8][3],
    const _Float16* Ah, const _Float16* Al,
    const _Float16* __restrict__ Wth, const _Float16* __restrict__ Wtl,
    int col0, int kk, int quad, int lr){
#pragma unroll
  for (int c = 0; c < 2; ++c){
    const int ro = c * 32 + quad * 8;
    h8 amh[MI], aml[MI];
#pragma unroll
    for (int mi = 0; mi < MI; ++mi){
      const int r = (mi * 16 + lr) * GPITCH + ro;
      amh[mi] = *(const h8*)&Ah[r]; aml[mi] = *(const h8*)&Al[r];
    }
#pragma unroll
    for (int ni = 0; ni < 3; ++ni){
      const size_t rb = ((size_t)(col0 + ni * 16 + lr)) * HID + kk + ro;
      h8 bh = ldh(Wth + rb), bl = ldh(Wtl + rb);     // L2-resident weights
#pragma unroll
      for (int mi = 0; mi < MI; ++mi){
        acc[mi][ni] = mfma16h(amh[mi], bh, acc[mi][ni]);
        acc[mi][ni] = mfma16h(amh[mi], bl, acc[mi][ni]);
        acc[mi][ni] = mfma16h(aml[mi], bh, acc[mi][ni]);
      }
    }
  }
}

template <int MI>
__device__ __forceinline__ void g2n_epi(const f4 (&acc)[8][3],
    const float* __restrict__ rb, const float* __restrict__ Cs,
    float* __restrict__ S, int b, int gr0, int len, int col0, int quad, int lr){
#pragma unroll
  for (int ni = 0; ni < 3; ++ni){
    const int col = col0 + ni * 16 + lr;
    const float yv = rb[col];
    const float y0 = fast_tanh(yv);
    float csum = 0.f;
#pragma unroll
    for (int mi = 0; mi < MI; ++mi)
#pragma unroll
      for (int r = 0; r < 4; ++r){
        const int rl = mi * 16 + quad * 4 + r;              // within sentence
        const int grow = gr0 + rl;                          // global token row
        const float f = sigmoid_c(acc[mi][ni][r]);
        const float omf = 1.f - f;
        const float xv = sane(Cs[(size_t)grow * HID + col]);
        const float x0 = fast_tanh(xv);
        const float outv = f * f * x0 + f * xv + omf * omf * y0 + omf * yv;
        csum += (rl < len) ? outv : 0.f;
      }
    csum += __shfl_xor(csum, 16);
    csum += __shfl_xor(csum, 32);
    if (quad == 0) S[(size_t)b * HID + col] = csum;         // exclusive: plain store
  }
}

// ---------------- G2 (per iteration): FULL SENTENCE (M=128) per block ------------
// v5: one block per sentence (grid 512, all live). 8 waves x 48 cols, acc[8][3]
// = 96 AGPR (~210 unified -> 1 block / 8 waves resident, which matches the ~9
// waves/CU measured for every prior config). Mechanism: convoys per CU drop
// 18 -> 12 (3 blocks x 6 K-steps -> 2 x 6), W2 L2-traffic -33%, 12:1
// MFMA-per-B-load, and S becomes exclusive per block -> plain stores, no
// atomics, no memset, no S-zeroing in stageD2. len<=64 sentences take the
// compile-time MI=4 path (no extra MFMA work vs the old dead-half skip).
__global__ void __launch_bounds__(512, 2) k_g2n(
    const _Float16* __restrict__ P0h, const _Float16* __restrict__ P0l,
    const _Float16* __restrict__ Wth, const _Float16* __restrict__ Wtl,
    const float* __restrict__ yw1, const float* __restrict__ Cs,
    const float* __restrict__ r_inte,
    const int* __restrict__ lens, float* __restrict__ S){
  __shared__ _Float16 Ah[128*GPITCH], Al[128*GPITCH];   // 18.4 KB each
  __shared__ float ywS[HID];                            // 1.5 KB
  const int t = threadIdx.x;
  const int wave = t >> 6, lane = t & 63, quad = lane >> 4, lr = lane & 15;
  const int b = blockIdx.x;            // one sentence per block
  const int len = lens[b];
  const int gr0 = b * SLEN;
  const int srow = t >> 3;             // staging rows srow and srow+64
  const int sk8 = (t & 7) << 3;
  const int col0 = wave * 48;
  const bool hi = (len > 64);
  if (t < HID) ywS[t] = yw1[(size_t)b * HID + t];
  __syncthreads();
  const _Float16* pb0 = P0h + (size_t)(gr0 + srow) * HID + sk8;
  const _Float16* lb0 = P0l + (size_t)(gr0 + srow) * HID + sk8;
  const _Float16* pb1 = pb0 + (size_t)64 * HID;
  const _Float16* lb1 = lb0 + (size_t)64 * HID;
  h8 ph0 = ldh(pb0), pl0 = ldh(lb0), ph1 = {}, pl1 = {};
  if (hi){ ph1 = ldh(pb1); pl1 = ldh(lb1); }
  f4 acc[8][3] = {};
  for (int ks = 0; ks < 6; ++ks){
    const int kk = ks * 64;
    {   // A-stage: T = tanh(P0.hi + P0.lo + yw1), split to hi/lo planes
      const f4 ywa = *(const f4*)&ywS[kk + sk8];
      const f4 ywb = *(const f4*)&ywS[kk + sk8 + 4];
      h8 th, tl;
#pragma unroll
      for (int j = 0; j < 8; ++j){
        const float yw = (j < 4) ? ywa[j] : ywb[j - 4];
        float x = fast_tanh((float)ph0[j] + (float)pl0[j] + yw);
        _Float16 h = (_Float16)x;
        th[j] = h; tl[j] = (_Float16)(x - (float)h);
      }
      *(h8*)&Ah[srow * GPITCH + sk8] = th;
      *(h8*)&Al[srow * GPITCH + sk8] = tl;
      if (hi){
        h8 th1, tl1;
#pragma unroll
        for (int j = 0; j < 8; ++j){
          const float yw = (j < 4) ? ywa[j] : ywb[j - 4];
          float x = fast_tanh((float)ph1[j] + (float)pl1[j] + yw);
          _Float16 h = (_Float16)x;
          th1[j] = h; tl1[j] = (_Float16)(x - (float)h);
        }
        *(h8*)&Ah[(64 + srow) * GPITCH + sk8] = th1;
        *(h8*)&Al[(64 + srow) * GPITCH + sk8] = tl1;
      }
    }
    if (ks < 5){                       // prefetch next K-step's P0 rows
      ph0 = ldh(pb0 + kk + 64); pl0 = ldh(lb0 + kk + 64);
      if (hi){ ph1 = ldh(pb1 + kk + 64); pl1 = ldh(lb1 + kk + 64); }
    }
    bar_lds();
    if (hi) g2n_mfma<8>(acc, Ah, Al, Wth, Wtl, col0, kk, quad, lr);
    else    g2n_mfma<4>(acc, Ah, Al, Wth, Wtl, col0, kk, quad, lr);
    bar_lds();
  }
  const float* rb = r_inte + (size_t)b * HID;
  if (hi) g2n_epi<8>(acc, rb, Cs, S, b, gr0, len, col0, quad, lr);
  else    g2n_epi<4>(acc, rb, Cs, S, b, gr0, len, col0, quad, lr);
}

// ---------------- stage D v2: fss -> rates -> softmax -> f_inte -> r_inte -> yw1 ----
__global__ void k_stageD2(
    const float* __restrict__ Cs, const float* __restrict__ Hm,
    const float* __restrict__ ci, const float* __restrict__ Vsc,
    const float* __restrict__ W1c, const float* __restrict__ w35,
    const float* __restrict__ hy, const int* __restrict__ lens,
    const float* __restrict__ S, float* __restrict__ fss_g,
    float* __restrict__ r_inte, float* __restrict__ yw1){
  const int b = blockIdx.x;
  const int t = threadIdx.x;            // 384 threads = 6 waves
  const int len = lens[b];
  __shared__ float Sl[HID], fssS[HID], fssw[HID], tri[HID];
  __shared__ float rates[SLEN];
  __shared__ float wA[SLEN], wB[SLEN], wC[SLEN], wD[SLEN];
  // phase 0: fss = S @ V_SF (S written exclusively by g2n; no zeroing needed)
  Sl[t] = S[(size_t)b * HID + t];
  __syncthreads();
  {
    float s = 0.f;
    for (int k = 0; k < HID; ++k) s += Sl[k] * Vsc[(size_t)k * HID + t];
    const float fs = clampf(s, -1e30f, 1e30f);
    fssS[t] = fs; fssw[t] = fs * w35[t];
    fss_g[(size_t)b * HID + t] = fs;
  }
  __syncthreads();
  // phase 1: rates
  const int wave = t >> 6, lane = t & 63;
  for (int l = wave; l < SLEN; l += 6){
    const float* row = Cs + ((size_t)b * SLEN + l) * HID;
    float s = 0.f;
#pragma unroll
    for (int i = 0; i < 6; ++i){ int k = lane + 64 * i; s += sane(row[k]) * fssw[k]; }
    for (int off = 32; off; off >>= 1) s += __shfl_down(s, off);
    if (lane == 0) rates[l] = clampf(s + hy[(size_t)b * SLEN + l], -1e30f, 1e30f);
  }
  __syncthreads();
  // phase 2: masked softmax -> fusion weights
  if (wave == 0){
    float r0 = (lane < len) ? rates[lane] : -3.0e38f;
    float r1 = (lane + 64 < len) ? rates[lane + 64] : -3.0e38f;
    float mx = fmaxf(r0, r1);
    for (int off = 32; off; off >>= 1) mx = fmaxf(mx, __shfl_xor(mx, off));
    float e0 = (lane < len) ? __expf(r0 - mx) : 0.f;
    float e1 = (lane + 64 < len) ? __expf(r1 - mx) : 0.f;
    float sm = e0 + e1;
    for (int off = 32; off; off >>= 1) sm += __shfl_xor(sm, off);
    const float inv = (sm > 0.f) ? (1.f / sm) : 0.f;
    float a0 = clampf(e0 * inv, 0.f, 1.f), a1 = clampf(e1 * inv, 0.f, 1.f);
    wA[lane] = a0 * a0; wB[lane] = a0;
    wC[lane] = (1.f - a0) * (1.f - a0); wD[lane] = 1.f - a0;
    wA[lane + 64] = a1 * a1; wB[lane + 64] = a1;
    wC[lane + 64] = (1.f - a1) * (1.f - a1); wD[lane + 64] = 1.f - a1;
  }
  __syncthreads();
  // phase 3: f_inte -> r_inte
  {
    const float fs = fssS[t];
    float acc = 0.f;
#pragma unroll 4
    for (int l = 0; l < len; ++l){
      const float cv = sane(Cs[((size_t)b * SLEN + l) * HID + t]);
      const float hv = sane(Hm[((size_t)b * SLEN + l) * HID + t]);
      const float rs = fs * cv;
      acc += wA[l] * fast_tanh(rs) + wB[l] * rs + wC[l] * fast_tanh(hv) + wD[l] * hv;
    }
    const float ri = clampf(acc + sane(ci[(size_t)b * HID + t]), -1e30f, 1e30f);
    r_inte[(size_t)b * HID + t] = ri;
    tri[t] = fast_tanh(ri);
  }
  __syncthreads();
  // phase 4: next-iteration yw1 = tanh(r_inte) @ W1
  {
    float s = 0.f;
    for (int k = 0; k < HID; ++k) s += tri[k] * W1c[(size_t)k * HID + t];
    yw1[(size_t)b * HID + t] = clampf(s, -1e30f, 1e30f);
  }
}

// ---------------- output heads (fp32 outputs) ----------------
__global__ void k_intent(const float* __restrict__ r_inte, const float* __restrict__ Wit,
                         float* __restrict__ out){
  const int t = threadIdx.x;                 // block 128: 4 sentences x 32 labels
  const int b = blockIdx.x * 4 + (t >> 5);
  const int n = t & 31;
  const float* wr = Wit + (size_t)n * HID;
  const float* rr = r_inte + (size_t)b * HID;
  float s = 0.f;
  for (int k = 0; k < HID; ++k) s += rr[k] * wr[k];
  out[(size_t)b * NLAB + n] = clampf(s, -3e38f, 3e38f);
}

// slot_output = [H | fss(b).*c] @ W_slot, split-bf16 3-product, dead waves write 0.
__global__ void __launch_bounds__(256, 2) k_slot_bf(
    const float* __restrict__ Hm, const float* __restrict__ Cs,
    const float* __restrict__ fss, const int* __restrict__ lens,
    const __bf16* __restrict__ Wth, const __bf16* __restrict__ Wtl,
    float* __restrict__ out){
  const int wave = threadIdx.x >> 6, lane = threadIdx.x & 63;
  const int quad = lane >> 4, lr = lane & 15;
  const int m0 = blockIdx.x * 128 + (wave & 1) * 64;
  const int n0 = (wave >> 1) * 64;
  const int b = blockIdx.x;
  const int ko = quad * 8;
  const int len = lens[b];
  if ((wave & 1) * 64 >= len){
#pragma unroll
    for (int mi = 0; mi < 4; ++mi)
#pragma unroll
      for (int ni = 0; ni < 4; ++ni)
#pragma unroll
        for (int r = 0; r < 4; ++r){
          const int row = m0 + mi * 16 + quad * 4 + r;
          const int col = n0 + ni * 16 + lr;
          out[(size_t)row * NSLOT + col] = 0.f;
        }
    return;
  }
  f4 acc[4][4] = {};
  for (int kk = 0; kk < 2 * HID; kk += 32){
    b8 ah[4], al[4], bh[4], bl[4];
#pragma unroll
    for (int i = 0; i < 4; ++i){
      size_t rb = (size_t)(n0 + i * 16 + lr) * (2 * HID) + kk + ko;
      bh[i] = ldb(Wth + rb); bl[i] = ldb(Wtl + rb);
    }
    if (kk < HID){
#pragma unroll
      for (int i = 0; i < 4; ++i){
        const float* hrow = Hm + (size_t)(m0 + i * 16 + lr) * HID + kk + ko;
        b8 vh, vl;
#pragma unroll
        for (int j = 0; j < 8; ++j){
          float v = sane(hrow[j]);
          __bf16 h = (__bf16)v;
          vh[j] = h; vl[j] = (__bf16)(v - (float)h);
        }
        ah[i] = vh; al[i] = vl;
      }
    } else {
      const int k2 = kk - HID + ko;
      float fv[8];
#pragma unroll
      for (int j = 0; j < 8; ++j) fv[j] = fss[(size_t)b * HID + k2 + j];
#pragma unroll
      for (int i = 0; i < 4; ++i){
        const float* crow = Cs + (size_t)(m0 + i * 16 + lr) * HID + k2;
        b8 vh, vl;
#pragma unroll
        for (int j = 0; j < 8; ++j){
          float v = fv[j] * sane(crow[j]);
          __bf16 h = (__bf16)v;
          vh[j] = h; vl[j] = (__bf16)(v - (float)h);
        }
        ah[i] = vh; al[i] = vl;
      }
    }
#pragma unroll
    for (int mi = 0; mi < 4; ++mi)
#pragma unroll
      for (int ni = 0; ni < 4; ++ni){
        acc[mi][ni] = mfma16b(ah[mi], bh[ni], acc[mi][ni]);
        acc[mi][ni] = mfma16b(ah[mi], bl[ni], acc[mi][ni]);
        acc[mi][ni] = mfma16b(al[mi], bh[ni], acc[mi][ni]);
      }
  }
#pragma unroll
  for (int mi = 0; mi < 4; ++mi)
#pragma unroll
    for (int ni = 0; ni < 4; ++ni)
#pragma unroll
      for (int r = 0; r < 4; ++r){
        const int row = m0 + mi * 16 + quad * 4 + r;
        const int col = n0 + ni * 16 + lr;
        out[(size_t)row * NSLOT + col] = clampf(acc[mi][ni][r], -3e38f, 3e38f);
      }
}

// ---------------- launch ----------------
extern "C" void kernel_launch(void* const* d_in, const int* in_sizes, int n_in,
                              void* d_out, int out_size, void* d_ws, size_t ws_size,
                              hipStream_t stream){
  (void)in_sizes; (void)n_in; (void)out_size;
  const float* Hm  = (const float*)d_in[0];
  const float* Cs  = (const float*)d_in[1];
  const float* ci  = (const float*)d_in[2];
  const float* W0  = (const float*)d_in[3];
  const float* W1  = (const float*)d_in[4];
  const float* W2  = (const float*)d_in[5];
  const float* W3  = (const float*)d_in[6];
  const float* W4  = (const float*)d_in[7];
  const float* b4  = (const float*)d_in[8];
  const float* W5  = (const float*)d_in[9];
  const float* Vs  = (const float*)d_in[10];
  const float* Wi  = (const float*)d_in[11];
  const float* Wsl = (const float*)d_in[12];
  const int* lens_raw = (const int*)d_in[13];
  // d_in[14] = iteration_num = 3 (hard-coded)

  char* base = (char*)d_ws;
  size_t off = 0;
  auto alloc = [&](size_t bytes) -> void* {
    void* p = base + off; off += (bytes + 255) & ~(size_t)255; return p;
  };
  const size_t NT = (size_t)MTOK * HID;
  _Float16* P0h  = (_Float16*)alloc(NT * 2);
  _Float16* P0l  = (_Float16*)alloc(NT * 2);
  _Float16* W0th = (_Float16*)alloc((size_t)HID * HID * 2);
  _Float16* W0tl = (_Float16*)alloc((size_t)HID * HID * 2);
  _Float16* W2th = (_Float16*)alloc((size_t)HID * HID * 2);
  _Float16* W2tl = (_Float16*)alloc((size_t)HID * HID * 2);
  __bf16*   Wsth = (__bf16*)alloc((size_t)2 * HID * NSLOT * 2);
  __bf16*   Wstl = (__bf16*)alloc((size_t)2 * HID * NSLOT * 2);
  float* W1c    = (float*)alloc((size_t)HID * HID * 4);
  float* Vsc    = (float*)alloc((size_t)HID * HID * 4);
  float* Wit    = (float*)alloc((size_t)HID * NLAB * 4);
  float* w35    = (float*)alloc(HID * 4);
  float* w45    = (float*)alloc(HID * 4);
  float* b45    = (float*)alloc(4);
  float* hy     = (float*)alloc((size_t)MTOK * 4);
  float* yw1    = (float*)alloc((size_t)NB * HID * 4);
  float* r_inte = (float*)alloc((size_t)NB * HID * 4);
  float* S      = (float*)alloc((size_t)NB * HID * 4);
  float* fss    = (float*)alloc((size_t)NB * HID * 4);
  int* lensN    = (int*)alloc((size_t)NB * 4);
  if (off > ws_size) return;

  k_lens<<<1, NB, 0, stream>>>(lens_raw, lensN);
  k_wsplit16<<<(HID * HID + 255) / 256, 256, 0, stream>>>(W0, W0th, W0tl, HID, HID);
  k_wsplit16<<<(HID * HID + 255) / 256, 256, 0, stream>>>(W2, W2th, W2tl, HID, HID);
  k_wsplitbf<<<(2 * HID * NSLOT + 255) / 256, 256, 0, stream>>>(Wsl, Wsth, Wstl, 2 * HID, NSLOT);
  k_sanecopy<<<(HID * HID + 255) / 256, 256, 0, stream>>>(W1, W1c, HID * HID);
  k_sanecopy<<<(HID * HID + 255) / 256, 256, 0, stream>>>(Vs, Vsc, HID * HID);
  k_transpose32<<<(HID * NLAB + 255) / 256, 256, 0, stream>>>(Wi, Wit, HID, NLAB);
  k_w35<<<1, HID, 0, stream>>>(W3, W4, b4, W5, w35, w45, b45);
  k_hy<<<MTOK / 4, 256, 0, stream>>>(Hm, w45, b45, hy);
  k_p0c<<<MTOK / 64, 512, 0, stream>>>(Cs, W0th, W0tl, lensN, P0h, P0l);

  // initial: r_inte = sane(ci); yw1 = tanh(r_inte) @ W1  (k_ci folded in)
  k_vecmat<1, 1><<<NB, HID, 0, stream>>>(ci, W1c, yw1, r_inte);

  for (int it = 0; it < 3; ++it){
    k_g2n<<<NB, 512, 0, stream>>>(P0h, P0l, W2th, W2tl, yw1, Cs, r_inte, lensN, S);
    k_stageD2<<<NB, HID, 0, stream>>>(Cs, Hm, ci, Vsc, W1c, w35, hy, lensN,
                                      S, fss, r_inte, yw1);
  }

  float* outp = (float*)d_out;
  k_intent<<<NB / 4, 128, 0, stream>>>(r_inte, Wit, outp);
  k_slot_bf<<<NB, 256, 0, stream>>>(Hm, Cs, fss, lensN, Wsth, Wstl, outp + (size_t)NB * NLAB);
}

// Round 8
// 970.727 us; speedup vs baseline: 1.1185x; 1.0273x over previous
//
#include <hip/hip_runtime.h>
#include <math.h>

#define HID 384
#define SLEN 128
#define NB 512
#define MTOK (NB*SLEN)   // 65536 tokens
#define NLAB 32
#define NSLOT 128
#define GPITCH 72        // LDS fp16 pitch (64 K + 8 pad): 144B stride = 2-way bank alias (free)

typedef _Float16 h8 __attribute__((ext_vector_type(8)));
typedef _Float16 h4v __attribute__((ext_vector_type(4)));
typedef __bf16   b8 __attribute__((ext_vector_type(8)));
typedef float    f4 __attribute__((ext_vector_type(4)));

// ---- NaN-proof primitives ----
__device__ __forceinline__ float sane(float x){
  return __builtin_isfinite(x) ? x : 0.f;
}
__device__ __forceinline__ float clampf(float x, float lo, float hi){
  return fminf(hi, fmaxf(lo, x));                      // NaN -> lo (finite)
}
__device__ __forceinline__ float fast_rcp(float x){
  return __builtin_amdgcn_rcpf(x);
}
__device__ __forceinline__ float fast_tanh(float x){
  x = clampf(x, -15.f, 15.f);
  float e = __expf(2.f * x);
  return (e - 1.f) * fast_rcp(e + 1.f);
}
__device__ __forceinline__ float sigmoid_c(float x){
  x = clampf(x, -60.f, 60.f);
  return fast_rcp(1.f + __expf(-x));
}
__device__ __forceinline__ void split16(float x, _Float16* h, _Float16* l){
  _Float16 hh = (_Float16)x; *h = hh; *l = (_Float16)(x - (float)hh);
}
__device__ __forceinline__ h8 ldh(const _Float16* p){ return *reinterpret_cast<const h8*>(p); }
__device__ __forceinline__ b8 ldb(const __bf16* p){ return *reinterpret_cast<const b8*>(p); }
__device__ __forceinline__ f4 mfma16h(h8 a, h8 b, f4 c){
  return __builtin_amdgcn_mfma_f32_16x16x32_f16(a, b, c, 0, 0, 0);
}
__device__ __forceinline__ f4 mfma16b(b8 a, b8 b, f4 c){
  return __builtin_amdgcn_mfma_f32_16x16x32_bf16(a, b, c, 0, 0, 0);
}
// LDS-only barrier: waits LDS ops, does NOT drain vmcnt -> global loads stay
// in flight across it. All global loads in kernels using this are
// thread-private (register dest), so no cross-thread visibility is needed.
__device__ __forceinline__ void bar_lds(){
  asm volatile("s_waitcnt lgkmcnt(0)" ::: "memory");
  __builtin_amdgcn_s_barrier();
}

// ---------------- setup kernels ----------------

__global__ void k_lens(const int* __restrict__ raw, int* __restrict__ lensN){
  const int b = threadIdx.x;          // block = NB = 512
  __shared__ int is64;
  if (b == 0) is64 = (raw[1] == 0) ? 1 : 0;
  __syncthreads();
  int v = is64 ? raw[2 * b] : raw[b];
  v = v < 0 ? 0 : (v > SLEN ? SLEN : v);
  lensN[b] = v;
}

// transposed fp16 hi/lo split
__global__ void k_wsplit16(const float* __restrict__ in, _Float16* __restrict__ outh,
                           _Float16* __restrict__ outl, int R, int C){
  int idx = blockIdx.x * blockDim.x + threadIdx.x;
  if (idx < R * C){
    int r = idx / C, c = idx - r * C;
    float v = sane(in[idx]);
    _Float16 h = (_Float16)v;
    outh[(size_t)c * R + r] = h;
    outl[(size_t)c * R + r] = (_Float16)(v - (float)h);
  }
}

// transposed bf16 hi/lo split (slot head weights)
__global__ void k_wsplitbf(const float* __restrict__ in, __bf16* __restrict__ outh,
                           __bf16* __restrict__ outl, int R, int C){
  int idx = blockIdx.x * blockDim.x + threadIdx.x;
  if (idx < R * C){
    int r = idx / C, c = idx - r * C;
    float v = sane(in[idx]);
    __bf16 h = (__bf16)v;
    outh[(size_t)c * R + r] = h;
    outl[(size_t)c * R + r] = (__bf16)(v - (float)h);
  }
}

__global__ void k_transpose32(const float* __restrict__ in, float* __restrict__ out,
                              int R, int C){
  int idx = blockIdx.x * blockDim.x + threadIdx.x;
  if (idx < R * C){ int r = idx / C, c = idx - r * C; out[(size_t)c * R + r] = sane(in[idx]); }
}

// sanitize-copy (keeps dot-phase weights in original [k][t] layout, coalesced)
__global__ void k_sanecopy(const float* __restrict__ in, float* __restrict__ out, int n){
  int i = blockIdx.x * blockDim.x + threadIdx.x;
  if (i < n) out[i] = sane(in[i]);
}

__global__ void k_w35(const float* __restrict__ W3, const float* __restrict__ W4,
                      const float* __restrict__ b4, const float* __restrict__ W5,
                      float* __restrict__ w35, float* __restrict__ w45, float* __restrict__ b45){
  __shared__ float w5s[HID];
  int t = threadIdx.x;                     // block = 384
  w5s[t] = sane(W5[t]);
  __syncthreads();
  float s3 = 0.f, s4 = 0.f;
  for (int j = 0; j < HID; ++j){
    float w5 = w5s[j];
    s3 += sane(W3[(size_t)t * HID + j]) * w5;
    s4 += sane(W4[(size_t)t * HID + j]) * w5;
  }
  w35[t] = s3; w45[t] = s4;
  if (t == 0){
    float s = 0.f;
    for (int j = 0; j < HID; ++j) s += sane(b4[j]) * w5s[j];
    *b45 = s;
  }
}

// hy for LIVE tokens only (dead rows never read: stageD2 phase 1 is len-bounded)
__global__ void k_hy(const float* __restrict__ Hm, const float* __restrict__ w45,
                     const float* __restrict__ b45, const int* __restrict__ lens,
                     float* __restrict__ hy){
  int wave = threadIdx.x >> 6, lane = threadIdx.x & 63;
  int tok = blockIdx.x * 4 + wave;
  const int b = tok >> 7, l = tok & (SLEN - 1);
  if (l >= lens[b]) return;            // wave-uniform skip of padded tokens
  const float* row = Hm + (size_t)tok * HID;
  float s = 0.f;
#pragma unroll
  for (int i = 0; i < 6; ++i){ int k = lane + 64 * i; s += sane(row[k]) * w45[k]; }
  for (int off = 32; off; off >>= 1) s += __shfl_down(s, off);
  if (lane == 0) hy[tok] = clampf(s + *b45, -1e30f, 1e30f);
}

// ---------------- small GEMM (fp32). SANE_IN: sanitize input and store the
// sanitized pre-tanh value to pre_store (folds the old k_ci copy kernel). ----
template <int TANH, int SANE_IN>
__global__ void k_vecmat(const float* __restrict__ in, const float* __restrict__ W,
                         float* __restrict__ out, float* __restrict__ pre_store){
  const int b = blockIdx.x, t = threadIdx.x;   // block = 384
  __shared__ float v[HID];
  float x = in[(size_t)b * HID + t];
  if (SANE_IN) x = sane(x);
  if (pre_store) pre_store[(size_t)b * HID + t] = x;
  if (TANH) x = fast_tanh(x);
  v[t] = x;
  __syncthreads();
  float s = 0.f;
  for (int k = 0; k < HID; ++k) s += v[k] * W[(size_t)k * HID + t];
  out[(size_t)b * HID + t] = clampf(s, -1e30f, 1e30f);
}

// ---- shared MFMA phase: MI row-fragments x 3 col-fragments, BK=64 ----------
template <int MI>
__device__ __forceinline__ void mfma_phase(f4 (&acc)[MI][3],
    const _Float16* Ah, const _Float16* Al,
    const _Float16* __restrict__ Wth, const _Float16* __restrict__ Wtl,
    int col0, int kk, int quad, int lr){
#pragma unroll
  for (int c = 0; c < 2; ++c){
    const int ro = c * 32 + quad * 8;
    h8 amh[MI], aml[MI];
#pragma unroll
    for (int mi = 0; mi < MI; ++mi){
      const int r = (mi * 16 + lr) * GPITCH + ro;
      amh[mi] = *(const h8*)&Ah[r]; aml[mi] = *(const h8*)&Al[r];
    }
#pragma unroll
    for (int ni = 0; ni < 3; ++ni){
      const size_t rb = ((size_t)(col0 + ni * 16 + lr)) * HID + kk + ro;
      h8 bh = ldh(Wth + rb), bl = ldh(Wtl + rb);     // L2-resident weights
#pragma unroll
      for (int mi = 0; mi < MI; ++mi){
        acc[mi][ni] = mfma16h(amh[mi], bh, acc[mi][ni]);
        acc[mi][ni] = mfma16h(amh[mi], bl, acc[mi][ni]);
        acc[mi][ni] = mfma16h(aml[mi], bh, acc[mi][ni]);
      }
    }
  }
}

// ---------------- P0 = tanh(Cs) @ W0 (setup) ----------------
// M=64 blocks (2 resident/CU kept — cross-block overlap matters), 8 waves x
// 48 cols, single tanh+split. NEW: LDS A double-buffer -> ONE barrier per
// K-step (the write-after-read hazard that forced the 2nd barrier is gone:
// iteration ks writes the buffer read at ks-1, whose reads completed before
// the bar_lds at the end of ks-1 via lgkmcnt(0)). Bit-identical arithmetic.
__global__ void __launch_bounds__(512, 4) k_p0c(
    const float* __restrict__ Cs,
    const _Float16* __restrict__ Wth, const _Float16* __restrict__ Wtl,
    const int* __restrict__ lens,
    _Float16* __restrict__ P0h, _Float16* __restrict__ P0l){
  __shared__ _Float16 Ah[2][64*GPITCH], Al[2][64*GPITCH];   // 2 x 9 KB each
  const int t = threadIdx.x;
  const int wave = t >> 6, lane = t & 63, quad = lane >> 4, lr = lane & 15;
  const int bx = blockIdx.x;           // 64-row group (half sentence)
  const int b = bx >> 1;
  const int len = lens[b];
  const int row0 = (bx & 1) * 64;
  if (row0 >= len) return;             // dead half: P0 rows never read live
  const int gr0 = bx * 64;
  const int srow = t >> 3;             // staging: 8 threads/row, 8 K-els each
  const int sk8 = (t & 7) << 3;
  const int col0 = wave * 48;
  const float* abase = Cs + (size_t)(gr0 + srow) * HID + sk8;

  auto stage = [&](int buf, f4 c0, f4 c1){
    h8 th, tl;
#pragma unroll
    for (int j = 0; j < 8; ++j){
      float x = fast_tanh(sane((j < 4) ? c0[j] : c1[j - 4]));
      _Float16 h = (_Float16)x;
      th[j] = h; tl[j] = (_Float16)(x - (float)h);
    }
    *(h8*)&Ah[buf][srow * GPITCH + sk8] = th;
    *(h8*)&Al[buf][srow * GPITCH + sk8] = tl;
  };

  f4 acc[4][3] = {};
  f4 c0 = *(const f4*)(abase), c1 = *(const f4*)(abase + 4);
  stage(0, c0, c1);                    // prologue: stage ks=0
  c0 = *(const f4*)(abase + 64); c1 = *(const f4*)(abase + 68);   // prefetch ks=1
  bar_lds();
  for (int ks = 0; ks < 6; ++ks){
    const int cur = ks & 1;
    if (ks < 5){
      stage(cur ^ 1, c0, c1);          // stage ks+1 into the other buffer
      if (ks < 4){
        c0 = *(const f4*)(abase + (ks + 2) * 64);
        c1 = *(const f4*)(abase + (ks + 2) * 64 + 4);
      }
    }
    mfma_phase<4>(acc, &Ah[cur][0], &Al[cur][0], Wth, Wtl, col0, ks * 64, quad, lr);
    bar_lds();                         // single barrier per K-step
  }
  // epilogue: split-store live rows of the wave's 48 cols
#pragma unroll
  for (int ni = 0; ni < 3; ++ni){
    const int col = col0 + ni * 16 + lr;
#pragma unroll
    for (int mi = 0; mi < 4; ++mi)
#pragma unroll
      for (int r = 0; r < 4; ++r){
        const int rl = row0 + mi * 16 + quad * 4 + r;
        if (rl < len){
          const size_t o = ((size_t)(b * SLEN + rl)) * HID + col;
          _Float16 h, l; split16(acc[mi][ni][r], &h, &l);
          P0h[o] = h; P0l[o] = l;
        }
      }
  }
}

// ---- G2 epilogue: sigmoid-fusion + masked row-reduce, exclusive col store ----
template <int MI>
__device__ __forceinline__ void g2n_epi(const f4 (&acc)[MI][3],
    const float* __restrict__ rb, const float* __restrict__ Cs,
    float* __restrict__ S, int b, int gr0, int len, int col0, int quad, int lr){
#pragma unroll
  for (int ni = 0; ni < 3; ++ni){
    const int col = col0 + ni * 16 + lr;
    const float yv = rb[col];
    const float y0 = fast_tanh(yv);
    float csum = 0.f;
#pragma unroll
    for (int mi = 0; mi < MI; ++mi)
#pragma unroll
      for (int r = 0; r < 4; ++r){
        const int rl = mi * 16 + quad * 4 + r;              // within sentence
        const int grow = gr0 + rl;                          // global token row
        const float f = sigmoid_c(acc[mi][ni][r]);
        const float omf = 1.f - f;
        const float xv = sane(Cs[(size_t)grow * HID + col]);
        const float x0 = fast_tanh(xv);
        const float outv = f * f * x0 + f * xv + omf * omf * y0 + omf * yv;
        csum += (rl < len) ? outv : 0.f;
      }
    csum += __shfl_xor(csum, 16);
    csum += __shfl_xor(csum, 32);
    if (quad == 0) S[(size_t)b * HID + col] = csum;         // exclusive: plain store
  }
}

// ---- G2 core (MI = 4 for len<=64, 8 for len>64), LDS A double-buffered ----
template <int MI>
__device__ __forceinline__ void g2n_core(
    _Float16 (&Ah)[2][128*GPITCH], _Float16 (&Al)[2][128*GPITCH],
    const float* ywS,
    const _Float16* __restrict__ P0h, const _Float16* __restrict__ P0l,
    const _Float16* __restrict__ Wth, const _Float16* __restrict__ Wtl,
    const float* __restrict__ Cs, const float* __restrict__ r_inte,
    float* __restrict__ S, int b, int len,
    int srow, int sk8, int col0, int quad, int lr){
  const int gr0 = b * SLEN;
  const _Float16* pb0 = P0h + (size_t)(gr0 + srow) * HID + sk8;
  const _Float16* lb0 = P0l + (size_t)(gr0 + srow) * HID + sk8;
  const _Float16* pb1 = pb0 + (size_t)64 * HID;
  const _Float16* lb1 = lb0 + (size_t)64 * HID;

  h8 ph0, pl0, ph1 = {}, pl1 = {};
  auto loadp = [&](int kk){
    ph0 = ldh(pb0 + kk); pl0 = ldh(lb0 + kk);
    if (MI == 8){ ph1 = ldh(pb1 + kk); pl1 = ldh(lb1 + kk); }
  };
  auto stage = [&](int buf, int kk){
    const f4 ywa = *(const f4*)&ywS[kk + sk8];
    const f4 ywb = *(const f4*)&ywS[kk + sk8 + 4];
    h8 th, tl;
#pragma unroll
    for (int j = 0; j < 8; ++j){
      const float yw = (j < 4) ? ywa[j] : ywb[j - 4];
      float x = fast_tanh((float)ph0[j] + (float)pl0[j] + yw);
      _Float16 h = (_Float16)x;
      th[j] = h; tl[j] = (_Float16)(x - (float)h);
    }
    *(h8*)&Ah[buf][srow * GPITCH + sk8] = th;
    *(h8*)&Al[buf][srow * GPITCH + sk8] = tl;
    if (MI == 8){
      h8 th1, tl1;
#pragma unroll
      for (int j = 0; j < 8; ++j){
        const float yw = (j < 4) ? ywa[j] : ywb[j - 4];
        float x = fast_tanh((float)ph1[j] + (float)pl1[j] + yw);
        _Float16 h = (_Float16)x;
        th1[j] = h; tl1[j] = (_Float16)(x - (float)h);
      }
      *(h8*)&Ah[buf][(64 + srow) * GPITCH + sk8] = th1;
      *(h8*)&Al[buf][(64 + srow) * GPITCH + sk8] = tl1;
    }
  };

  f4 acc[MI][3] = {};
  loadp(0);
  stage(0, 0);                         // prologue: stage ks=0
  loadp(64);                           // prefetch ks=1
  bar_lds();
  for (int ks = 0; ks < 6; ++ks){
    const int cur = ks & 1;
    if (ks < 5){
      stage(cur ^ 1, (ks + 1) * 64);   // stage ks+1 into the other buffer
      if (ks < 4) loadp((ks + 2) * 64);
    }
    mfma_phase<MI>(acc, &Ah[cur][0], &Al[cur][0], Wth, Wtl, col0, ks * 64, quad, lr);
    bar_lds();                         // single barrier per K-step
  }
  const float* rb = r_inte + (size_t)b * HID;
  g2n_epi<MI>(acc, rb, Cs, S, b, gr0, len, col0, quad, lr);
}

// ---------------- G2 (per iteration): FULL SENTENCE (M=128) per block ------------
// One block per sentence (grid 512, all live), 8 waves x 48 cols. S exclusive
// per block -> plain stores, no atomics/memsets. LDS A dbuf -> 6 barriers
// total instead of 12.
__global__ void __launch_bounds__(512, 2) k_g2n(
    const _Float16* __restrict__ P0h, const _Float16* __restrict__ P0l,
    const _Float16* __restrict__ Wth, const _Float16* __restrict__ Wtl,
    const float* __restrict__ yw1, const float* __restrict__ Cs,
    const float* __restrict__ r_inte,
    const int* __restrict__ lens, float* __restrict__ S){
  __shared__ _Float16 Ah[2][128*GPITCH], Al[2][128*GPITCH];   // 2 x 18.4 KB each
  __shared__ float ywS[HID];                                  // 1.5 KB
  const int t = threadIdx.x;
  const int wave = t >> 6, lane = t & 63, quad = lane >> 4, lr = lane & 15;
  const int b = blockIdx.x;            // one sentence per block
  const int len = lens[b];
  const int srow = t >> 3;             // staging rows srow (and srow+64 if hi)
  const int sk8 = (t & 7) << 3;
  const int col0 = wave * 48;
  if (t < HID) ywS[t] = yw1[(size_t)b * HID + t];
  bar_lds();                           // ywS visible; global loads unaffected
  if (len > 64)
    g2n_core<8>(Ah, Al, ywS, P0h, P0l, Wth, Wtl, Cs, r_inte, S, b, len,
                srow, sk8, col0, quad, lr);
  else
    g2n_core<4>(Ah, Al, ywS, P0h, P0l, Wth, Wtl, Cs, r_inte, S, b, len,
                srow, sk8, col0, quad, lr);
}

// ---------------- stage D v2: fss -> rates -> softmax -> f_inte -> r_inte -> yw1 ----
__global__ void k_stageD2(
    const float* __restrict__ Cs, const float* __restrict__ Hm,
    const float* __restrict__ ci, const float* __restrict__ Vsc,
    const float* __restrict__ W1c, const float* __restrict__ w35,
    const float* __restrict__ hy, const int* __restrict__ lens,
    const float* __restrict__ S, float* __restrict__ fss_g,
    float* __restrict__ r_inte, float* __restrict__ yw1){
  const int b = blockIdx.x;
  const int t = threadIdx.x;            // 384 threads = 6 waves
  const int len = lens[b];
  __shared__ float Sl[HID], fssS[HID], fssw[HID], tri[HID];
  __shared__ float rates[SLEN];
  __shared__ float wA[SLEN], wB[SLEN], wC[SLEN], wD[SLEN];
  // phase 0: fss = S @ V_SF (S written exclusively by g2n; no zeroing needed)
  Sl[t] = S[(size_t)b * HID + t];
  __syncthreads();
  {
    float s = 0.f;
    for (int k = 0; k < HID; ++k) s += Sl[k] * Vsc[(size_t)k * HID + t];
    const float fs = clampf(s, -1e30f, 1e30f);
    fssS[t] = fs; fssw[t] = fs * w35[t];
    fss_g[(size_t)b * HID + t] = fs;
  }
  __syncthreads();
  // phase 1: rates — live rows only (rates[l>=len] provably unread)
  const int wave = t >> 6, lane = t & 63;
  for (int l = wave; l < len; l += 6){
    const float* row = Cs + ((size_t)b * SLEN + l) * HID;
    float s = 0.f;
#pragma unroll
    for (int i = 0; i < 6; ++i){ int k = lane + 64 * i; s += sane(row[k]) * fssw[k]; }
    for (int off = 32; off; off >>= 1) s += __shfl_down(s, off);
    if (lane == 0) rates[l] = clampf(s + hy[(size_t)b * SLEN + l], -1e30f, 1e30f);
  }
  __syncthreads();
  // phase 2: masked softmax -> fusion weights
  if (wave == 0){
    float r0 = (lane < len) ? rates[lane] : -3.0e38f;
    float r1 = (lane + 64 < len) ? rates[lane + 64] : -3.0e38f;
    float mx = fmaxf(r0, r1);
    for (int off = 32; off; off >>= 1) mx = fmaxf(mx, __shfl_xor(mx, off));
    float e0 = (lane < len) ? __expf(r0 - mx) : 0.f;
    float e1 = (lane + 64 < len) ? __expf(r1 - mx) : 0.f;
    float sm = e0 + e1;
    for (int off = 32; off; off >>= 1) sm += __shfl_xor(sm, off);
    const float inv = (sm > 0.f) ? (1.f / sm) : 0.f;
    float a0 = clampf(e0 * inv, 0.f, 1.f), a1 = clampf(e1 * inv, 0.f, 1.f);
    wA[lane] = a0 * a0; wB[lane] = a0;
    wC[lane] = (1.f - a0) * (1.f - a0); wD[lane] = 1.f - a0;
    wA[lane + 64] = a1 * a1; wB[lane + 64] = a1;
    wC[lane + 64] = (1.f - a1) * (1.f - a1); wD[lane + 64] = 1.f - a1;
  }
  __syncthreads();
  // phase 3: f_inte -> r_inte
  {
    const float fs = fssS[t];
    float acc = 0.f;
#pragma unroll 4
    for (int l = 0; l < len; ++l){
      const float cv = sane(Cs[((size_t)b * SLEN + l) * HID + t]);
      const float hv = sane(Hm[((size_t)b * SLEN + l) * HID + t]);
      const float rs = fs * cv;
      acc += wA[l] * fast_tanh(rs) + wB[l] * rs + wC[l] * fast_tanh(hv) + wD[l] * hv;
    }
    const float ri = clampf(acc + sane(ci[(size_t)b * HID + t]), -1e30f, 1e30f);
    r_inte[(size_t)b * HID + t] = ri;
    tri[t] = fast_tanh(ri);
  }
  __syncthreads();
  // phase 4: next-iteration yw1 = tanh(r_inte) @ W1
  {
    float s = 0.f;
    for (int k = 0; k < HID; ++k) s += tri[k] * W1c[(size_t)k * HID + t];
    yw1[(size_t)b * HID + t] = clampf(s, -1e30f, 1e30f);
  }
}

// ---------------- output heads (fp32 outputs) ----------------
__global__ void k_intent(const float* __restrict__ r_inte, const float* __restrict__ Wit,
                         float* __restrict__ out){
  const int t = threadIdx.x;                 // block 128: 4 sentences x 32 labels
  const int b = blockIdx.x * 4 + (t >> 5);
  const int n = t & 31;
  const float* wr = Wit + (size_t)n * HID;
  const float* rr = r_inte + (size_t)b * HID;
  float s = 0.f;
  for (int k = 0; k < HID; ++k) s += rr[k] * wr[k];
  out[(size_t)b * NLAB + n] = clampf(s, -3e38f, 3e38f);
}

// slot_output = [H | fss(b).*c] @ W_slot, split-bf16 3-product, dead waves write 0.
__global__ void __launch_bounds__(256, 2) k_slot_bf(
    const float* __restrict__ Hm, const float* __restrict__ Cs,
    const float* __restrict__ fss, const int* __restrict__ lens,
    const __bf16* __restrict__ Wth, const __bf16* __restrict__ Wtl,
    float* __restrict__ out){
  const int wave = threadIdx.x >> 6, lane = threadIdx.x & 63;
  const int quad = lane >> 4, lr = lane & 15;
  const int m0 = blockIdx.x * 128 + (wave & 1) * 64;
  const int n0 = (wave >> 1) * 64;
  const int b = blockIdx.x;
  const int ko = quad * 8;
  const int len = lens[b];
  if ((wave & 1) * 64 >= len){
#pragma unroll
    for (int mi = 0; mi < 4; ++mi)
#pragma unroll
      for (int ni = 0; ni < 4; ++ni)
#pragma unroll
        for (int r = 0; r < 4; ++r){
          const int row = m0 + mi * 16 + quad * 4 + r;
          const int col = n0 + ni * 16 + lr;
          out[(size_t)row * NSLOT + col] = 0.f;
        }
    return;
  }
  f4 acc[4][4] = {};
  for (int kk = 0; kk < 2 * HID; kk += 32){
    b8 ah[4], al[4], bh[4], bl[4];
#pragma unroll
    for (int i = 0; i < 4; ++i){
      size_t rb = (size_t)(n0 + i * 16 + lr) * (2 * HID) + kk + ko;
      bh[i] = ldb(Wth + rb); bl[i] = ldb(Wtl + rb);
    }
    if (kk < HID){
#pragma unroll
      for (int i = 0; i < 4; ++i){
        const float* hrow = Hm + (size_t)(m0 + i * 16 + lr) * HID + kk + ko;
        b8 vh, vl;
#pragma unroll
        for (int j = 0; j < 8; ++j){
          float v = sane(hrow[j]);
          __bf16 h = (__bf16)v;
          vh[j] = h; vl[j] = (__bf16)(v - (float)h);
        }
        ah[i] = vh; al[i] = vl;
      }
    } else {
      const int k2 = kk - HID + ko;
      float fv[8];
#pragma unroll
      for (int j = 0; j < 8; ++j) fv[j] = fss[(size_t)b * HID + k2 + j];
#pragma unroll
      for (int i = 0; i < 4; ++i){
        const float* crow = Cs + (size_t)(m0 + i * 16 + lr) * HID + k2;
        b8 vh, vl;
#pragma unroll
        for (int j = 0; j < 8; ++j){
          float v = fv[j] * sane(crow[j]);
          __bf16 h = (__bf16)v;
          vh[j] = h; vl[j] = (__bf16)(v - (float)h);
        }
        ah[i] = vh; al[i] = vl;
      }
    }
#pragma unroll
    for (int mi = 0; mi < 4; ++mi)
#pragma unroll
      for (int ni = 0; ni < 4; ++ni){
        acc[mi][ni] = mfma16b(ah[mi], bh[ni], acc[mi][ni]);
        acc[mi][ni] = mfma16b(ah[mi], bl[ni], acc[mi][ni]);
        acc[mi][ni] = mfma16b(al[mi], bh[ni], acc[mi][ni]);
      }
  }
#pragma unroll
  for (int mi = 0; mi < 4; ++mi)
#pragma unroll
    for (int ni = 0; ni < 4; ++ni)
#pragma unroll
      for (int r = 0; r < 4; ++r){
        const int row = m0 + mi * 16 + quad * 4 + r;
        const int col = n0 + ni * 16 + lr;
        out[(size_t)row * NSLOT + col] = clampf(acc[mi][ni][r], -3e38f, 3e38f);
      }
}

// ---------------- launch ----------------
extern "C" void kernel_launch(void* const* d_in, const int* in_sizes, int n_in,
                              void* d_out, int out_size, void* d_ws, size_t ws_size,
                              hipStream_t stream){
  (void)in_sizes; (void)n_in; (void)out_size;
  const float* Hm  = (const float*)d_in[0];
  const float* Cs  = (const float*)d_in[1];
  const float* ci  = (const float*)d_in[2];
  const float* W0  = (const float*)d_in[3];
  const float* W1  = (const float*)d_in[4];
  const float* W2  = (const float*)d_in[5];
  const float* W3  = (const float*)d_in[6];
  const float* W4  = (const float*)d_in[7];
  const float* b4  = (const float*)d_in[8];
  const float* W5  = (const float*)d_in[9];
  const float* Vs  = (const float*)d_in[10];
  const float* Wi  = (const float*)d_in[11];
  const float* Wsl = (const float*)d_in[12];
  const int* lens_raw = (const int*)d_in[13];
  // d_in[14] = iteration_num = 3 (hard-coded)

  char* base = (char*)d_ws;
  size_t off = 0;
  auto alloc = [&](size_t bytes) -> void* {
    void* p = base + off; off += (bytes + 255) & ~(size_t)255; return p;
  };
  const size_t NT = (size_t)MTOK * HID;
  _Float16* P0h  = (_Float16*)alloc(NT * 2);
  _Float16* P0l  = (_Float16*)alloc(NT * 2);
  _Float16* W0th = (_Float16*)alloc((size_t)HID * HID * 2);
  _Float16* W0tl = (_Float16*)alloc((size_t)HID * HID * 2);
  _Float16* W2th = (_Float16*)alloc((size_t)HID * HID * 2);
  _Float16* W2tl = (_Float16*)alloc((size_t)HID * HID * 2);
  __bf16*   Wsth = (__bf16*)alloc((size_t)2 * HID * NSLOT * 2);
  __bf16*   Wstl = (__bf16*)alloc((size_t)2 * HID * NSLOT * 2);
  float* W1c    = (float*)alloc((size_t)HID * HID * 4);
  float* Vsc    = (float*)alloc((size_t)HID * HID * 4);
  float* Wit    = (float*)alloc((size_t)HID * NLAB * 4);
  float* w35    = (float*)alloc(HID * 4);
  float* w45    = (float*)alloc(HID * 4);
  float* b45    = (float*)alloc(4);
  float* hy     = (float*)alloc((size_t)MTOK * 4);
  float* yw1    = (float*)alloc((size_t)NB * HID * 4);
  float* r_inte = (float*)alloc((size_t)NB * HID * 4);
  float* S      = (float*)alloc((size_t)NB * HID * 4);
  float* fss    = (float*)alloc((size_t)NB * HID * 4);
  int* lensN    = (int*)alloc((size_t)NB * 4);
  if (off > ws_size) return;

  k_lens<<<1, NB, 0, stream>>>(lens_raw, lensN);
  k_wsplit16<<<(HID * HID + 255) / 256, 256, 0, stream>>>(W0, W0th, W0tl, HID, HID);
  k_wsplit16<<<(HID * HID + 255) / 256, 256, 0, stream>>>(W2, W2th, W2tl, HID, HID);
  k_wsplitbf<<<(2 * HID * NSLOT + 255) / 256, 256, 0, stream>>>(Wsl, Wsth, Wstl, 2 * HID, NSLOT);
  k_sanecopy<<<(HID * HID + 255) / 256, 256, 0, stream>>>(W1, W1c, HID * HID);
  k_sanecopy<<<(HID * HID + 255) / 256, 256, 0, stream>>>(Vs, Vsc, HID * HID);
  k_transpose32<<<(HID * NLAB + 255) / 256, 256, 0, stream>>>(Wi, Wit, HID, NLAB);
  k_w35<<<1, HID, 0, stream>>>(W3, W4, b4, W5, w35, w45, b45);
  k_hy<<<MTOK / 4, 256, 0, stream>>>(Hm, w45, b45, lensN, hy);
  k_p0c<<<MTOK / 64, 512, 0, stream>>>(Cs, W0th, W0tl, lensN, P0h, P0l);

  // initial: r_inte = sane(ci); yw1 = tanh(r_inte) @ W1  (k_ci folded in)
  k_vecmat<1, 1><<<NB, HID, 0, stream>>>(ci, W1c, yw1, r_inte);

  for (int it = 0; it < 3; ++it){
    k_g2n<<<NB, 512, 0, stream>>>(P0h, P0l, W2th, W2tl, yw1, Cs, r_inte, lensN, S);
    k_stageD2<<<NB, HID, 0, stream>>>(Cs, Hm, ci, Vsc, W1c, w35, hy, lensN,
                                      S, fss, r_inte, yw1);
  }

  float* outp = (float*)d_out;
  k_intent<<<NB / 4, 128, 0, stream>>>(r_inte, Wit, outp);
  k_slot_bf<<<NB, 256, 0, stream>>>(Hm, Cs, fss, lensN, Wsth, Wstl, outp + (size_t)NB * NLAB);
}